// Round 11
// baseline (136.383 us; speedup 1.0000x reference)
//
#include <hip/hip_runtime.h>
#include <cstdint>

#define BB 8
#define NN 2048
#define CC 64
#define TI 128           // i-rows per block (8 waves x 16)
#define JSPLIT 2
#define KRANGE (NN / JSPLIT)   // 1024 j per block
#define JCH 128                // adj reg-prefetch chunk
#define NCH (KRANGE / JCH)     // 8

typedef __attribute__((ext_vector_type(8))) _Float16 f16x8;
typedef __attribute__((ext_vector_type(4))) float f32x4;
typedef __attribute__((ext_vector_type(4))) unsigned int u32x4;
typedef __attribute__((ext_vector_type(4))) int i32x4;

// ws layout (in floats):
static const size_t WS_E1  = 0;                                  // B*N
static const size_t WS_E2  = WS_E1 + (size_t)BB*NN;              // B*N
static const size_t WS_HT  = WS_E2 + (size_t)BB*NN;              // hT fp16: B*C*N ushorts
static const size_t WS_ACC = WS_HT + (size_t)BB*CC*NN/2;         // JSPLIT*B*N*C floats
static const size_t WS_Z   = WS_ACC + (size_t)JSPLIT*BB*NN*CC;   // JSPLIT*B*N

#define GL16(g, l) __builtin_amdgcn_global_load_lds( \
    (const __attribute__((address_space(1))) void*)(g), \
    (__attribute__((address_space(3))) void*)(uint32_t)(uintptr_t)(l), 16, 0, 0)
#define GL4(g, l) __builtin_amdgcn_global_load_lds( \
    (const __attribute__((address_space(1))) void*)(g), \
    (__attribute__((address_space(3))) void*)(uint32_t)(uintptr_t)(l), 4, 0, 0)
#define WAIT0()  asm volatile("s_waitcnt vmcnt(0)" ::: "memory")
#define BAR()    __builtin_amdgcn_s_barrier()

// ---------------- Kernel 1 (fused): h=inp@W in-register; e1,e2; hT fp16 transposed ----------------
// grid 256 (b x 32 row-tiles) @ 256 thr. Thread (rg=t>>6, c=t&63) computes h for rows
// rg*16..+15 at column c (identical fmaf chain to the old k1 -> bit-identical hT).
__global__ __launch_bounds__(256) void k1_fused(const float* __restrict__ inp,
        const float* __restrict__ Wm, const float* __restrict__ av,
        unsigned short* __restrict__ hT, float* __restrict__ e1, float* __restrict__ e2) {
    __shared__ float inpL[64][65];
    __shared__ float WL[64][65];
    int t = threadIdx.x;
    int b = blockIdx.x >> 5;
    int i0 = (blockIdx.x & 31) * 64;
    const float* ib = inp + ((size_t)b * NN + i0) * CC;
    #pragma unroll
    for (int q = 0; q < 16; q++) {
        int idx = q * 256 + t;
        inpL[idx >> 6][idx & 63] = ib[idx];
        WL[idx >> 6][idx & 63]   = Wm[idx];
    }
    __syncthreads();
    int rg = t >> 6;
    int c  = t & 63;
    float a1 = av[c], a2 = av[64 + c];
    float hv[16];
    #pragma unroll
    for (int p = 0; p < 16; p++) {
        float acc = 0.f;
        #pragma unroll
        for (int k = 0; k < 64; k++) acc = fmaf(inpL[rg * 16 + p][k], WL[k][c], acc);
        hv[p] = acc;
    }
    #pragma unroll
    for (int p = 0; p < 16; p++) {
        float v1 = hv[p] * a1;
        float v2 = hv[p] * a2;
        #pragma unroll
        for (int o = 32; o > 0; o >>= 1) {
            v1 += __shfl_down(v1, o);
            v2 += __shfl_down(v2, o);
        }
        if (c == 0) {
            size_t row = (size_t)b * NN + i0 + rg * 16 + p;
            e1[row] = v1;
            e2[row] = v2;
        }
    }
    unsigned int uh[8];
    #pragma unroll
    for (int p8 = 0; p8 < 8; p8++) {
        unsigned int pack = 0;
        #pragma unroll
        for (int ss = 0; ss < 2; ss++) {
            _Float16 fh = (_Float16)hv[p8 * 2 + ss];
            pack |= ((unsigned int)__builtin_bit_cast(unsigned short, fh)) << (16 * ss);
        }
        uh[p8] = pack;
    }
    size_t off = ((size_t)b * 64 + c) * NN + i0 + rg * 16;   // ushorts
    u32x4* dh = (u32x4*)(hT + off);
    dh[0] = u32x4{uh[0], uh[1], uh[2], uh[3]};
    dh[1] = u32x4{uh[4], uh[5], uh[6], uh[7]};
}

// ---------------- Kernel 2: fp16 MFMA attention; h-half LDS-resident; 3-deep adj prefetch ----------------
// grid 256 @ 512 thr: bid = (tile<<4)|(s<<3)|b; b = bid&7 (XCD<->batch affinity).
// h-half (64ch x 1024 fp16 = 128 KB) staged once; barrier-free main loop; adj prefetched
// 3 chunks deep (aA/aB/aC rotation, ~2 chunk-times ~ 900+ cyc cover for HBM latency).
__global__ __launch_bounds__(512, 1) void k2_mfma(const int* __restrict__ adj,
        const unsigned short* __restrict__ hT,
        const float* __restrict__ e1, const float* __restrict__ e2,
        float* __restrict__ accp, float* __restrict__ zp) {
    __shared__ __align__(16) char smem[135168];   // 128 KB h + 4 KB e2
    float* e2L = (float*)(smem + 131072);

    int bid = blockIdx.x;
    int b    = bid & 7;
    int rest = bid >> 3;
    int s    = rest & 1;
    int tile = rest >> 1;          // 0..15
    int i0 = tile * TI;
    int jbase = s * KRANGE;

    int t = threadIdx.x;
    int w = t >> 6;
    int l = t & 63;
    int col = l & 15;
    int kg  = l >> 4;              // k-group 0..3

    const int* adjrow = adj + ((size_t)b * NN + i0 + w * 16 + col) * NN + jbase;
    float e1v = e1[(size_t)b * NN + i0 + w * 16 + col];
    const float* e2b = e2 + (size_t)b * NN;
    const unsigned short* hTb = hT + (size_t)b * 64 * NN;

    f32x4 acc[4];
    #pragma unroll
    for (int n = 0; n < 4; n++) acc[n] = f32x4{0.f, 0.f, 0.f, 0.f};
    f32x4 accZ = f32x4{0.f, 0.f, 0.f, 0.f};

    _Float16 onev = (_Float16)1.0f, zerov = (_Float16)0.0f;
    f16x8 onesf;
    #pragma unroll
    for (int i = 0; i < 8; i++) onesf[i] = (col == 0) ? onev : zerov;

    i32x4 aA[8], aB[8], aC[8];

#define ADJP(jcN, arr) { \
    _Pragma("unroll") \
    for (int q = 0; q < 4; q++) { \
        const i32x4* ap = (const i32x4*)(adjrow + (jcN) * JCH + q * 32 + kg * 8); \
        arr[2 * q]     = ap[0]; \
        arr[2 * q + 1] = ap[1]; \
    } \
}

#define COMPUTE(jcN, arr) { \
    _Pragma("unroll") \
    for (int ks4 = 0; ks4 < 4; ks4++) { \
        int ks = (jcN) * 4 + ks4; \
        int krel = ks * 32 + kg * 8; \
        i32x4 a0 = arr[2 * ks4]; \
        i32x4 a1 = arr[2 * ks4 + 1]; \
        f32x4 e20 = *(const f32x4*)(e2L + krel); \
        f32x4 e21 = *(const f32x4*)(e2L + krel + 4); \
        float xs[8] = {e20.x, e20.y, e20.z, e20.w, e21.x, e21.y, e21.z, e21.w}; \
        int ms[8] = {a0.x, a0.y, a0.z, a0.w, a1.x, a1.y, a1.z, a1.w}; \
        f16x8 pf; \
        _Pragma("unroll") \
        for (int i = 0; i < 8; i++) { \
            float x = e1v + xs[i]; \
            x = fmaxf(x, 0.01f * x); \
            x = __expf(x); \
            x = (ms[i] > 0) ? x : 0.0f; \
            pf[i] = (_Float16)x; \
        } \
        int g = ks * 4 + kg; \
        _Pragma("unroll") \
        for (int n = 0; n < 4; n++) { \
            int c = n * 16 + col; \
            int p = (g & 120) | ((g ^ c) & 7); \
            f16x8 hv = __builtin_bit_cast(f16x8, *(const f32x4*)(smem + c * 2048 + p * 16)); \
            acc[n] = __builtin_amdgcn_mfma_f32_16x16x32_f16(pf, hv, acc[n], 0, 0, 0); \
        } \
        accZ = __builtin_amdgcn_mfma_f32_16x16x32_f16(pf, onesf, accZ, 0, 0, 0); \
    } \
}

    // ---- adj chunks 0..2 prefetch first: latency overlaps the h staging ----
    ADJP(0, aA);
    ADJP(1, aB);
    ADJP(2, aC);

    // ---- stage h-half (128 KB) once: 16 GL16 per wave, swizzled global source ----
    #pragma unroll
    for (int it = 0; it < 16; it++) {
        int k16 = it * 8 + w;            // half-row index 0..127 (wave-uniform)
        int c   = k16 >> 1;              // LDS row
        int p   = (k16 & 1) * 64 + l;    // physical granule within row
        int g   = (p & 120) | ((p ^ c) & 7);   // logical granule (involution)
        const unsigned short* src = hTb + (size_t)c * NN + jbase + g * 8;
        GL16(src, smem + (size_t)k16 * 1024);
    }
    // ---- stage e2 half-slice (4 KB) once ----
    #pragma unroll
    for (int it = 0; it < 2; it++) {
        GL4(e2b + jbase + it * 512 + w * 64 + l,
            smem + 131072 + (it * 512 + w * 64) * 4);
    }
    WAIT0();
    BAR();

    // ---- barrier-free main loop, 3-buffer rotation (issue k+3 right after compute k) ----
    COMPUTE(0, aA); ADJP(3, aA);
    COMPUTE(1, aB); ADJP(4, aB);
    COMPUTE(2, aC); ADJP(5, aC);
    COMPUTE(3, aA); ADJP(6, aA);
    COMPUTE(4, aB); ADJP(7, aB);
    COMPUTE(5, aC);
    COMPUTE(6, aA);
    COMPUTE(7, aB);

    // ---- epilogue: partial acc/Z to ws (C/D layout: col=lane&15, row=kg*4+reg) ----
    size_t orow = (size_t)s * BB * NN + (size_t)b * NN + i0 + w * 16 + kg * 4;
    float* accout = accp + orow * CC;
    #pragma unroll
    for (int n = 0; n < 4; n++) {
        #pragma unroll
        for (int r = 0; r < 4; r++) {
            accout[(size_t)r * CC + n * 16 + col] = acc[n][r];
        }
    }
    if (col == 0) {
        #pragma unroll
        for (int r = 0; r < 4; r++) zp[orow + r] = accZ[r];
    }
#undef ADJP
#undef COMPUTE
}

// ---------------- Kernel 3: out = sum_s acc[s] / sum_s z[s] ----------------
__global__ __launch_bounds__(256) void k3_final(const float* __restrict__ accp,
        const float* __restrict__ zp, float* __restrict__ out) {
    int idx = blockIdx.x * 256 + threadIdx.x;      // float4 index
    const int TOT4 = BB * NN * CC / 4;             // 262144
    if (idx >= TOT4) return;
    int row = idx >> 4;
    f32x4 s0 = ((const f32x4*)accp)[idx];
    f32x4 s1 = ((const f32x4*)accp)[idx + TOT4];
    float z = zp[row] + zp[row + BB * NN];
    float inv = (z > 0.f) ? (1.0f / z) : 0.f;
    f32x4 o;
    o.x = (s0.x + s1.x) * inv;
    o.y = (s0.y + s1.y) * inv;
    o.z = (s0.z + s1.z) * inv;
    o.w = (s0.w + s1.w) * inv;
    ((f32x4*)out)[idx] = o;
}

extern "C" void kernel_launch(void* const* d_in, const int* in_sizes, int n_in,
                              void* d_out, int out_size, void* d_ws, size_t ws_size,
                              hipStream_t stream) {
    const float* inp = (const float*)d_in[0];
    const int*   adj = (const int*)d_in[1];
    const float* Wm  = (const float*)d_in[2];
    const float* av  = (const float*)d_in[3];
    float* ws = (float*)d_ws;
    float* e1   = ws + WS_E1;
    float* e2   = ws + WS_E2;
    unsigned short* hT = (unsigned short*)(ws + WS_HT);
    float* accp = ws + WS_ACC;
    float* zp   = ws + WS_Z;
    float* out  = (float*)d_out;

    k1_fused<<<BB * (NN / 64), 256, 0, stream>>>(inp, Wm, av, hT, e1, e2);
    k2_mfma<<<BB * (NN / TI) * JSPLIT, 512, 0, stream>>>(adj, hT, e1, e2, accp, zp);
    k3_final<<<(BB * NN * CC / 4 + 255) / 256, 256, 0, stream>>>(accp, zp, out);
}

// Round 12
// 48.022 us; speedup vs baseline: 2.8400x; 2.8400x over previous
//
#include <hip/hip_runtime.h>
#include <cstdint>

#define BB 8
#define NN 2048
#define CC 64
#define TI 128           // i-rows per block (8 waves x 16)
#define JSPLIT 2
#define KRANGE (NN / JSPLIT)   // 1024 j per block
#define JCH 128                // adj reg-prefetch chunk
#define NCH (KRANGE / JCH)     // 8

typedef __attribute__((ext_vector_type(8))) _Float16 f16x8;
typedef __attribute__((ext_vector_type(4))) float f32x4;
typedef __attribute__((ext_vector_type(4))) unsigned int u32x4;
typedef __attribute__((ext_vector_type(4))) int i32x4;

// ws layout (in floats):
static const size_t WS_H   = 0;                                  // B*N*C
static const size_t WS_E1  = WS_H  + (size_t)BB*NN*CC;           // B*N
static const size_t WS_E2  = WS_E1 + (size_t)BB*NN;              // B*N
static const size_t WS_HT  = WS_E2 + (size_t)BB*NN;              // hT fp16: B*C*N ushorts
static const size_t WS_ACC = WS_HT + (size_t)BB*CC*NN/2;         // JSPLIT*B*N*C floats
static const size_t WS_Z   = WS_ACC + (size_t)JSPLIT*BB*NN*CC;   // JSPLIT*B*N

#define GL16(g, l) __builtin_amdgcn_global_load_lds( \
    (const __attribute__((address_space(1))) void*)(g), \
    (__attribute__((address_space(3))) void*)(uint32_t)(uintptr_t)(l), 16, 0, 0)
#define GL4(g, l) __builtin_amdgcn_global_load_lds( \
    (const __attribute__((address_space(1))) void*)(g), \
    (__attribute__((address_space(3))) void*)(uint32_t)(uintptr_t)(l), 4, 0, 0)
#define WAIT0()  asm volatile("s_waitcnt vmcnt(0)" ::: "memory")
#define BAR()    __builtin_amdgcn_s_barrier()

// ---------------- Kernel 1: h = inp @ W ; e1 = h@a1 ; e2 = h@a2 (round-10 proven) ----------------
__global__ __launch_bounds__(256) void k1_proj(const float* __restrict__ inp,
        const float* __restrict__ Wm, const float* __restrict__ av,
        float* __restrict__ h, float* __restrict__ e1, float* __restrict__ e2) {
    __shared__ float inp_lds[256];
    int t = threadIdx.x;
    size_t base = (size_t)blockIdx.x * 256;
    inp_lds[t] = inp[base + t];
    __syncthreads();
    int r = t >> 6;
    int c = t & 63;
    const float* irow = &inp_lds[r * 64];
    float acc = 0.f;
    #pragma unroll
    for (int k = 0; k < 64; k++) acc = fmaf(irow[k], Wm[k * 64 + c], acc);
    size_t row = (size_t)blockIdx.x * 4 + r;
    h[row * 64 + c] = acc;
    float v1 = acc * av[c];
    float v2 = acc * av[64 + c];
    #pragma unroll
    for (int o = 32; o > 0; o >>= 1) {
        v1 += __shfl_down(v1, o);
        v2 += __shfl_down(v2, o);
    }
    if (c == 0) { e1[row] = v1; e2[row] = v2; }
}

// ---------------- Kernel 1b: transpose h -> fp16, layout [b][c][n] (round-10 proven) ----------------
__global__ __launch_bounds__(256) void k1b_transpose(const float* __restrict__ h,
        unsigned short* __restrict__ hT) {
    __shared__ float tile[64][65];
    int t = threadIdx.x;
    int b = blockIdx.x >> 5;           // N/64 = 32 tiles
    int i0 = (blockIdx.x & 31) * 64;
    const float* hb = h + ((size_t)b * NN + i0) * CC;
    #pragma unroll
    for (int q = 0; q < 16; q++) {
        int idx = q * 256 + t;
        tile[idx >> 6][idx & 63] = hb[idx];
    }
    __syncthreads();
    int c = t & 63;
    int rgrp = t >> 6;           // 4 groups of 16 rows
    unsigned int uh[8];
    #pragma unroll
    for (int p = 0; p < 8; p++) {
        unsigned int pack_h = 0;
        #pragma unroll
        for (int s = 0; s < 2; s++) {
            float v = tile[rgrp * 16 + p * 2 + s][c];
            _Float16 fh = (_Float16)v;
            unsigned int u = (unsigned int)__builtin_bit_cast(unsigned short, fh);
            pack_h |= u << (16 * s);
        }
        uh[p] = pack_h;
    }
    size_t off = ((size_t)b * 64 + c) * NN + i0 + rgrp * 16;   // in ushorts
    u32x4* dh = (u32x4*)(hT + off);
    dh[0] = u32x4{uh[0], uh[1], uh[2], uh[3]};
    dh[1] = u32x4{uh[4], uh[5], uh[6], uh[7]};
}

// ---------------- Kernel 2: fp16 MFMA attention; h-half LDS-resident; 3-deep adj prefetch ----------------
// grid 256 @ 512 thr: bid = (tile<<4)|(s<<3)|b; b = bid&7 (XCD<->batch affinity).
// h-half (64ch x 1024 fp16 = 128 KB) staged once; barrier-free main loop; adj prefetched
// 3 chunks deep (aA/aB/aC rotation ~ 2 chunk-times of cover for ~900cy HBM latency).
__global__ __launch_bounds__(512, 1) void k2_mfma(const int* __restrict__ adj,
        const unsigned short* __restrict__ hT,
        const float* __restrict__ e1, const float* __restrict__ e2,
        float* __restrict__ accp, float* __restrict__ zp) {
    __shared__ __align__(16) char smem[135168];   // 128 KB h + 4 KB e2
    float* e2L = (float*)(smem + 131072);

    int bid = blockIdx.x;
    int b    = bid & 7;
    int rest = bid >> 3;
    int s    = rest & 1;
    int tile = rest >> 1;          // 0..15
    int i0 = tile * TI;
    int jbase = s * KRANGE;

    int t = threadIdx.x;
    int w = t >> 6;
    int l = t & 63;
    int col = l & 15;
    int kg  = l >> 4;              // k-group 0..3

    const int* adjrow = adj + ((size_t)b * NN + i0 + w * 16 + col) * NN + jbase;
    float e1v = e1[(size_t)b * NN + i0 + w * 16 + col];
    const float* e2b = e2 + (size_t)b * NN;
    const unsigned short* hTb = hT + (size_t)b * 64 * NN;

    f32x4 acc[4];
    #pragma unroll
    for (int n = 0; n < 4; n++) acc[n] = f32x4{0.f, 0.f, 0.f, 0.f};
    f32x4 accZ = f32x4{0.f, 0.f, 0.f, 0.f};

    _Float16 onev = (_Float16)1.0f, zerov = (_Float16)0.0f;
    f16x8 onesf;
    #pragma unroll
    for (int i = 0; i < 8; i++) onesf[i] = (col == 0) ? onev : zerov;

    i32x4 aA[8], aB[8], aC[8];

#define ADJP(jcN, arr) { \
    _Pragma("unroll") \
    for (int q = 0; q < 4; q++) { \
        const i32x4* ap = (const i32x4*)(adjrow + (jcN) * JCH + q * 32 + kg * 8); \
        arr[2 * q]     = ap[0]; \
        arr[2 * q + 1] = ap[1]; \
    } \
}

#define COMPUTE(jcN, arr) { \
    _Pragma("unroll") \
    for (int ks4 = 0; ks4 < 4; ks4++) { \
        int ks = (jcN) * 4 + ks4; \
        int krel = ks * 32 + kg * 8; \
        i32x4 a0 = arr[2 * ks4]; \
        i32x4 a1 = arr[2 * ks4 + 1]; \
        f32x4 e20 = *(const f32x4*)(e2L + krel); \
        f32x4 e21 = *(const f32x4*)(e2L + krel + 4); \
        float xs[8] = {e20.x, e20.y, e20.z, e20.w, e21.x, e21.y, e21.z, e21.w}; \
        int ms[8] = {a0.x, a0.y, a0.z, a0.w, a1.x, a1.y, a1.z, a1.w}; \
        f16x8 pf; \
        _Pragma("unroll") \
        for (int i = 0; i < 8; i++) { \
            float x = e1v + xs[i]; \
            x = fmaxf(x, 0.01f * x); \
            x = __expf(x); \
            x = (ms[i] > 0) ? x : 0.0f; \
            pf[i] = (_Float16)x; \
        } \
        int g = ks * 4 + kg; \
        _Pragma("unroll") \
        for (int n = 0; n < 4; n++) { \
            int c = n * 16 + col; \
            int p = (g & 120) | ((g ^ c) & 7); \
            f16x8 hv = __builtin_bit_cast(f16x8, *(const f32x4*)(smem + c * 2048 + p * 16)); \
            acc[n] = __builtin_amdgcn_mfma_f32_16x16x32_f16(pf, hv, acc[n], 0, 0, 0); \
        } \
        accZ = __builtin_amdgcn_mfma_f32_16x16x32_f16(pf, onesf, accZ, 0, 0, 0); \
    } \
}

    // ---- adj chunks 0..2 prefetch first: latency overlaps the h staging ----
    ADJP(0, aA);
    ADJP(1, aB);
    ADJP(2, aC);

    // ---- stage h-half (128 KB) once: 16 GL16 per wave, swizzled global source ----
    #pragma unroll
    for (int it = 0; it < 16; it++) {
        int k16 = it * 8 + w;            // half-row index 0..127 (wave-uniform)
        int c   = k16 >> 1;              // LDS row
        int p   = (k16 & 1) * 64 + l;    // physical granule within row
        int g   = (p & 120) | ((p ^ c) & 7);   // logical granule (involution)
        const unsigned short* src = hTb + (size_t)c * NN + jbase + g * 8;
        GL16(src, smem + (size_t)k16 * 1024);
    }
    // ---- stage e2 half-slice (4 KB) once ----
    #pragma unroll
    for (int it = 0; it < 2; it++) {
        GL4(e2b + jbase + it * 512 + w * 64 + l,
            smem + 131072 + (it * 512 + w * 64) * 4);
    }
    WAIT0();
    BAR();

    // ---- barrier-free main loop, 3-buffer rotation (issue k+3 right after compute k) ----
    COMPUTE(0, aA); ADJP(3, aA);
    COMPUTE(1, aB); ADJP(4, aB);
    COMPUTE(2, aC); ADJP(5, aC);
    COMPUTE(3, aA); ADJP(6, aA);
    COMPUTE(4, aB); ADJP(7, aB);
    COMPUTE(5, aC);
    COMPUTE(6, aA);
    COMPUTE(7, aB);

    // ---- epilogue: partial acc/Z to ws (C/D layout: col=lane&15, row=kg*4+reg) ----
    size_t orow = (size_t)s * BB * NN + (size_t)b * NN + i0 + w * 16 + kg * 4;
    float* accout = accp + orow * CC;
    #pragma unroll
    for (int n = 0; n < 4; n++) {
        #pragma unroll
        for (int r = 0; r < 4; r++) {
            accout[(size_t)r * CC + n * 16 + col] = acc[n][r];
        }
    }
    if (col == 0) {
        #pragma unroll
        for (int r = 0; r < 4; r++) zp[orow + r] = accZ[r];
    }
#undef ADJP
#undef COMPUTE
}

// ---------------- Kernel 3: out = sum_s acc[s] / sum_s z[s] ----------------
__global__ __launch_bounds__(256) void k3_final(const float* __restrict__ accp,
        const float* __restrict__ zp, float* __restrict__ out) {
    int idx = blockIdx.x * 256 + threadIdx.x;      // float4 index
    const int TOT4 = BB * NN * CC / 4;             // 262144
    if (idx >= TOT4) return;
    int row = idx >> 4;
    f32x4 s0 = ((const f32x4*)accp)[idx];
    f32x4 s1 = ((const f32x4*)accp)[idx + TOT4];
    float z = zp[row] + zp[row + BB * NN];
    float inv = (z > 0.f) ? (1.0f / z) : 0.f;
    f32x4 o;
    o.x = (s0.x + s1.x) * inv;
    o.y = (s0.y + s1.y) * inv;
    o.z = (s0.z + s1.z) * inv;
    o.w = (s0.w + s1.w) * inv;
    ((f32x4*)out)[idx] = o;
}

extern "C" void kernel_launch(void* const* d_in, const int* in_sizes, int n_in,
                              void* d_out, int out_size, void* d_ws, size_t ws_size,
                              hipStream_t stream) {
    const float* inp = (const float*)d_in[0];
    const int*   adj = (const int*)d_in[1];
    const float* Wm  = (const float*)d_in[2];
    const float* av  = (const float*)d_in[3];
    float* ws = (float*)d_ws;
    float* h    = ws + WS_H;
    float* e1   = ws + WS_E1;
    float* e2   = ws + WS_E2;
    unsigned short* hT = (unsigned short*)(ws + WS_HT);
    float* accp = ws + WS_ACC;
    float* zp   = ws + WS_Z;
    float* out  = (float*)d_out;

    k1_proj<<<BB * NN / 4, 256, 0, stream>>>(inp, Wm, av, h, e1, e2);
    k1b_transpose<<<BB * (NN / 64), 256, 0, stream>>>(h, hT);
    k2_mfma<<<BB * (NN / TI) * JSPLIT, 512, 0, stream>>>(adj, hT, e1, e2, accp, zp);
    k3_final<<<(BB * NN * CC / 4 + 255) / 256, 256, 0, stream>>>(accp, zp, out);
}

// Round 13
// 46.357 us; speedup vs baseline: 2.9420x; 1.0359x over previous
//
#include <hip/hip_runtime.h>
#include <cstdint>

#define BB 8
#define NN 2048
#define CC 64
#define TI 128           // i-rows per block (8 waves x 16)
#define JSPLIT 4
#define KRANGE (NN / JSPLIT)   // 512 j per block
#define JCH 64                 // adj reg-prefetch chunk
#define NCH (KRANGE / JCH)     // 8

typedef __attribute__((ext_vector_type(8))) _Float16 f16x8;
typedef __attribute__((ext_vector_type(4))) float f32x4;
typedef __attribute__((ext_vector_type(4))) unsigned int u32x4;
typedef __attribute__((ext_vector_type(4))) int i32x4;

// ws layout (in floats):
static const size_t WS_H   = 0;                                  // B*N*C
static const size_t WS_E1  = WS_H  + (size_t)BB*NN*CC;           // B*N
static const size_t WS_E2  = WS_E1 + (size_t)BB*NN;              // B*N
static const size_t WS_HT  = WS_E2 + (size_t)BB*NN;              // hT fp16: B*C*N ushorts
static const size_t WS_ACC = WS_HT + (size_t)BB*CC*NN/2;         // JSPLIT*B*N*C floats
static const size_t WS_Z   = WS_ACC + (size_t)JSPLIT*BB*NN*CC;   // JSPLIT*B*N

#define GL16(g, l) __builtin_amdgcn_global_load_lds( \
    (const __attribute__((address_space(1))) void*)(g), \
    (__attribute__((address_space(3))) void*)(uint32_t)(uintptr_t)(l), 16, 0, 0)
#define GL4(g, l) __builtin_amdgcn_global_load_lds( \
    (const __attribute__((address_space(1))) void*)(g), \
    (__attribute__((address_space(3))) void*)(uint32_t)(uintptr_t)(l), 4, 0, 0)
#define WAIT0()  asm volatile("s_waitcnt vmcnt(0)" ::: "memory")
#define BAR()    __builtin_amdgcn_s_barrier()

// ---------------- Kernel 1: h = inp @ W ; e1 = h@a1 ; e2 = h@a2 (proven) ----------------
__global__ __launch_bounds__(256) void k1_proj(const float* __restrict__ inp,
        const float* __restrict__ Wm, const float* __restrict__ av,
        float* __restrict__ h, float* __restrict__ e1, float* __restrict__ e2) {
    __shared__ float inp_lds[256];
    int t = threadIdx.x;
    size_t base = (size_t)blockIdx.x * 256;
    inp_lds[t] = inp[base + t];
    __syncthreads();
    int r = t >> 6;
    int c = t & 63;
    const float* irow = &inp_lds[r * 64];
    float acc = 0.f;
    #pragma unroll
    for (int k = 0; k < 64; k++) acc = fmaf(irow[k], Wm[k * 64 + c], acc);
    size_t row = (size_t)blockIdx.x * 4 + r;
    h[row * 64 + c] = acc;
    float v1 = acc * av[c];
    float v2 = acc * av[64 + c];
    #pragma unroll
    for (int o = 32; o > 0; o >>= 1) {
        v1 += __shfl_down(v1, o);
        v2 += __shfl_down(v2, o);
    }
    if (c == 0) { e1[row] = v1; e2[row] = v2; }
}

// ---------------- Kernel 1b: transpose h -> fp16, layout [b][c][n] (proven) ----------------
__global__ __launch_bounds__(256) void k1b_transpose(const float* __restrict__ h,
        unsigned short* __restrict__ hT) {
    __shared__ float tile[64][65];
    int t = threadIdx.x;
    int b = blockIdx.x >> 5;           // N/64 = 32 tiles
    int i0 = (blockIdx.x & 31) * 64;
    const float* hb = h + ((size_t)b * NN + i0) * CC;
    #pragma unroll
    for (int q = 0; q < 16; q++) {
        int idx = q * 256 + t;
        tile[idx >> 6][idx & 63] = hb[idx];
    }
    __syncthreads();
    int c = t & 63;
    int rgrp = t >> 6;           // 4 groups of 16 rows
    unsigned int uh[8];
    #pragma unroll
    for (int p = 0; p < 8; p++) {
        unsigned int pack_h = 0;
        #pragma unroll
        for (int s = 0; s < 2; s++) {
            float v = tile[rgrp * 16 + p * 2 + s][c];
            _Float16 fh = (_Float16)v;
            unsigned int u = (unsigned int)__builtin_bit_cast(unsigned short, fh);
            pack_h |= u << (16 * s);
        }
        uh[p] = pack_h;
    }
    size_t off = ((size_t)b * 64 + c) * NN + i0 + rgrp * 16;   // in ushorts
    u32x4* dh = (u32x4*)(hT + off);
    dh[0] = u32x4{uh[0], uh[1], uh[2], uh[3]};
    dh[1] = u32x4{uh[4], uh[5], uh[6], uh[7]};
}

// ---------------- Kernel 2: fp16 MFMA attention; h-quarter LDS-resident; 2 blocks/CU ----------------
// grid 512 @ 512 thr: b = bid&7 (XCD<->batch affinity); rest: s = &3, tile = >>2.
// h-quarter (64ch x 512 fp16 = 64 KB) + e2 (2 KB) staged once -> 66 KB LDS -> 2 blocks/CU
// (16 waves/CU: 2x the adj-stream TLP of round 10). Barrier-free main loop, 2-deep adj
// prefetch (JCH=64 halves prefetch VGPRs; launch_bounds(512,4) caps at 128 VGPR).
// LDS rows 1024 B; granule g at physical p=(g&56)|((g^c)&7) (involution, both sides).
__global__ __launch_bounds__(512, 4) void k2_mfma(const int* __restrict__ adj,
        const unsigned short* __restrict__ hT,
        const float* __restrict__ e1, const float* __restrict__ e2,
        float* __restrict__ accp, float* __restrict__ zp) {
    __shared__ __align__(16) char smem[67584];   // 64 KB h + 2 KB e2
    float* e2L = (float*)(smem + 65536);

    int bid = blockIdx.x;
    int b    = bid & 7;
    int rest = bid >> 3;
    int s    = rest & 3;
    int tile = rest >> 2;          // 0..15
    int i0 = tile * TI;
    int jbase = s * KRANGE;

    int t = threadIdx.x;
    int w = t >> 6;
    int l = t & 63;
    int col = l & 15;
    int kg  = l >> 4;              // k-group 0..3

    const int* adjrow = adj + ((size_t)b * NN + i0 + w * 16 + col) * NN + jbase;
    float e1v = e1[(size_t)b * NN + i0 + w * 16 + col];
    const float* e2b = e2 + (size_t)b * NN;
    const unsigned short* hTb = hT + (size_t)b * 64 * NN;

    f32x4 acc[4];
    #pragma unroll
    for (int n = 0; n < 4; n++) acc[n] = f32x4{0.f, 0.f, 0.f, 0.f};
    f32x4 accZ = f32x4{0.f, 0.f, 0.f, 0.f};

    _Float16 onev = (_Float16)1.0f, zerov = (_Float16)0.0f;
    f16x8 onesf;
    #pragma unroll
    for (int i = 0; i < 8; i++) onesf[i] = (col == 0) ? onev : zerov;

    i32x4 aA[4], aB[4];

#define ADJP(jcN, arr) { \
    _Pragma("unroll") \
    for (int q = 0; q < 2; q++) { \
        const i32x4* ap = (const i32x4*)(adjrow + (jcN) * JCH + q * 32 + kg * 8); \
        arr[2 * q]     = ap[0]; \
        arr[2 * q + 1] = ap[1]; \
    } \
}

#define COMPUTE(jcN, arr) { \
    _Pragma("unroll") \
    for (int ks4 = 0; ks4 < 2; ks4++) { \
        int ks = (jcN) * 2 + ks4; \
        int krel = ks * 32 + kg * 8; \
        i32x4 a0 = arr[2 * ks4]; \
        i32x4 a1 = arr[2 * ks4 + 1]; \
        f32x4 e20 = *(const f32x4*)(e2L + krel); \
        f32x4 e21 = *(const f32x4*)(e2L + krel + 4); \
        float xs[8] = {e20.x, e20.y, e20.z, e20.w, e21.x, e21.y, e21.z, e21.w}; \
        int ms[8] = {a0.x, a0.y, a0.z, a0.w, a1.x, a1.y, a1.z, a1.w}; \
        f16x8 pf; \
        _Pragma("unroll") \
        for (int i = 0; i < 8; i++) { \
            float x = e1v + xs[i]; \
            x = fmaxf(x, 0.01f * x); \
            x = __expf(x); \
            x = (ms[i] > 0) ? x : 0.0f; \
            pf[i] = (_Float16)x; \
        } \
        int g = ks * 4 + kg; \
        _Pragma("unroll") \
        for (int n = 0; n < 4; n++) { \
            int c = n * 16 + col; \
            int p = (g & 56) | ((g ^ c) & 7); \
            f16x8 hv = __builtin_bit_cast(f16x8, *(const f32x4*)(smem + c * 1024 + p * 16)); \
            acc[n] = __builtin_amdgcn_mfma_f32_16x16x32_f16(pf, hv, acc[n], 0, 0, 0); \
        } \
        accZ = __builtin_amdgcn_mfma_f32_16x16x32_f16(pf, onesf, accZ, 0, 0, 0); \
    } \
}

    // ---- adj chunk 0 prefetch first: latency overlaps the h staging ----
    ADJP(0, aA);

    // ---- stage h-quarter (64 KB) once: 8 GL16 per wave, swizzled global source ----
    #pragma unroll
    for (int it = 0; it < 8; it++) {
        int c = it * 8 + w;              // LDS row 0..63 (wave-uniform)
        int p = l;                       // physical granule (lane)
        int g = (p & 56) | ((p ^ c) & 7);    // logical granule (involution)
        const unsigned short* src = hTb + (size_t)c * NN + jbase + g * 8;
        GL16(src, smem + (size_t)c * 1024);
    }
    // ---- stage e2 quarter-slice (2 KB) once: 1 GL4 per wave ----
    GL4(e2b + jbase + w * 64 + l, smem + 65536 + w * 256);
    WAIT0();
    BAR();

    // ---- barrier-free main loop, 2-deep rotation (round-10 proven pattern) ----
    #pragma unroll
    for (int jc = 0; jc < NCH; jc += 2) {
        ADJP(jc + 1, aB);
        COMPUTE(jc, aA);
        if (jc + 2 < NCH) ADJP(jc + 2, aA);
        COMPUTE(jc + 1, aB);
    }

    // ---- epilogue: partial acc/Z to ws (C/D layout: col=lane&15, row=kg*4+reg) ----
    size_t orow = (size_t)s * BB * NN + (size_t)b * NN + i0 + w * 16 + kg * 4;
    float* accout = accp + orow * CC;
    #pragma unroll
    for (int n = 0; n < 4; n++) {
        #pragma unroll
        for (int r = 0; r < 4; r++) {
            accout[(size_t)r * CC + n * 16 + col] = acc[n][r];
        }
    }
    if (col == 0) {
        #pragma unroll
        for (int r = 0; r < 4; r++) zp[orow + r] = accZ[r];
    }
#undef ADJP
#undef COMPUTE
}

// ---------------- Kernel 3: out = sum_s acc[s] / sum_s z[s] (4 splits) ----------------
__global__ __launch_bounds__(256) void k3_final(const float* __restrict__ accp,
        const float* __restrict__ zp, float* __restrict__ out) {
    int idx = blockIdx.x * 256 + threadIdx.x;      // float4 index
    const int TOT4 = BB * NN * CC / 4;             // 262144
    if (idx >= TOT4) return;
    int row = idx >> 4;
    f32x4 s0 = ((const f32x4*)accp)[idx];
    f32x4 s1 = ((const f32x4*)accp)[idx + TOT4];
    f32x4 s2 = ((const f32x4*)accp)[idx + 2 * TOT4];
    f32x4 s3 = ((const f32x4*)accp)[idx + 3 * TOT4];
    float z = zp[row] + zp[row + BB * NN] + zp[row + 2 * BB * NN] + zp[row + 3 * BB * NN];
    float inv = (z > 0.f) ? (1.0f / z) : 0.f;
    f32x4 o;
    o.x = (s0.x + s1.x + s2.x + s3.x) * inv;
    o.y = (s0.y + s1.y + s2.y + s3.y) * inv;
    o.z = (s0.z + s1.z + s2.z + s3.z) * inv;
    o.w = (s0.w + s1.w + s2.w + s3.w) * inv;
    ((f32x4*)out)[idx] = o;
}

extern "C" void kernel_launch(void* const* d_in, const int* in_sizes, int n_in,
                              void* d_out, int out_size, void* d_ws, size_t ws_size,
                              hipStream_t stream) {
    const float* inp = (const float*)d_in[0];
    const int*   adj = (const int*)d_in[1];
    const float* Wm  = (const float*)d_in[2];
    const float* av  = (const float*)d_in[3];
    float* ws = (float*)d_ws;
    float* h    = ws + WS_H;
    float* e1   = ws + WS_E1;
    float* e2   = ws + WS_E2;
    unsigned short* hT = (unsigned short*)(ws + WS_HT);
    float* accp = ws + WS_ACC;
    float* zp   = ws + WS_Z;
    float* out  = (float*)d_out;

    k1_proj<<<BB * NN / 4, 256, 0, stream>>>(inp, Wm, av, h, e1, e2);
    k1b_transpose<<<BB * (NN / 64), 256, 0, stream>>>(h, hT);
    k2_mfma<<<BB * (NN / TI) * JSPLIT, 512, 0, stream>>>(adj, hT, e1, e2, accp, zp);
    k3_final<<<(BB * NN * CC / 4 + 255) / 256, 256, 0, stream>>>(accp, zp, out);
}